// Round 8
// baseline (204.274 us; speedup 1.0000x reference)
//
#include <hip/hip_runtime.h>
#include <hip/hip_bf16.h>
#include <math.h>

typedef __attribute__((ext_vector_type(8))) short bf16x8;
typedef __attribute__((ext_vector_type(4))) short bf16x4;
typedef __attribute__((ext_vector_type(4))) float floatx4;

constexpr int kN  = 4096;
constexpr int kD  = 768;
constexpr int kH  = 12;
constexpr int kHD = 64;
constexpr int k3D = 2304;
// Q pre-scale: (1/sqrt(64)) * log2(e) so softmax runs in exp2 domain with no muls
constexpr float kQScale = 0.18033688011112042f;

static __device__ __forceinline__ short f2b(float f) {
    __hip_bfloat16 h = __float2bfloat16(f);
    return *reinterpret_cast<short*>(&h);
}

static __device__ __forceinline__ float fast_exp2(float x) {
#if __has_builtin(__builtin_amdgcn_exp2f)
    return __builtin_amdgcn_exp2f(x);
#else
    return exp2f(x);
#endif
}

// Async global->LDS DMA, 16B per lane. LDS dst is wave-uniform base + lane*16.
static __device__ __forceinline__ void async_copy16(const void* g, void* l) {
    __builtin_amdgcn_global_load_lds(
        (const __attribute__((address_space(1))) void*)g,
        (__attribute__((address_space(3))) void*)l, 16, 0, 0);
}

// Fused prep: section 0 = x fp32->bf16; section 1 = W_qkv transpose->bf16;
// section 2 = W_out transpose->bf16. One launch instead of three.
constexpr int kBlkX  = 1536;            // (4096*768/8)/256
constexpr int kBlkWq = 72 * 24;         // (2304/32) x (768/32)
constexpr int kBlkWo = 24 * 24;         // (768/32) x (768/32)

__global__ __launch_bounds__(256)
void prep(const float* __restrict__ x, const float* __restrict__ Wq,
          const float* __restrict__ Wo, short* __restrict__ Xb,
          short* __restrict__ WqT, short* __restrict__ WoT)
{
    const int bid = blockIdx.x;
    const int tid = threadIdx.x;
    if (bid < kBlkX) {
        const int i = bid * 256 + tid;
        const float4* s = reinterpret_cast<const float4*>(x + (size_t)i * 8);
        float4 a = s[0], b = s[1];
        bf16x8 v;
        v[0] = f2b(a.x); v[1] = f2b(a.y); v[2] = f2b(a.z); v[3] = f2b(a.w);
        v[4] = f2b(b.x); v[5] = f2b(b.y); v[6] = f2b(b.z); v[7] = f2b(b.w);
        *reinterpret_cast<bf16x8*>(Xb + (size_t)i * 8) = v;
        return;
    }
    // transpose sections: src[R][C] -> dst[C][R]
    const float* src; short* dst; int R, C, bx, by;
    if (bid < kBlkX + kBlkWq) {
        const int local = bid - kBlkX;
        src = Wq; dst = WqT; R = kD; C = k3D; bx = local % 72; by = local / 72;
    } else {
        const int local = bid - kBlkX - kBlkWq;
        src = Wo; dst = WoT; R = kD; C = kD; bx = local % 24; by = local / 24;
    }
    __shared__ float t[32][33];
    const int c0 = bx * 32, r0 = by * 32;
    const int tx = tid & 31, ty = tid >> 5;
    #pragma unroll
    for (int i = ty; i < 32; i += 8)
        t[i][tx] = src[(size_t)(r0 + i) * C + c0 + tx];
    __syncthreads();
    #pragma unroll
    for (int i = ty; i < 32; i += 8)
        dst[(size_t)(c0 + i) * R + r0 + tx] = f2b(t[tx][i]);
}

// C[M x N] = A[M x K] * BT[N x K]^T, bf16 in, fp32 acc. 128x128 tile, BK=32.
// Double-buffered async staging: prefetch tile k+1 into the other LDS buffer
// BEFORE computing tile k, one barrier per iter -> DMA latency hides under
// the frag-read + MFMA phase (critical here: only 0.75-2.25 blocks/CU, so
// cross-block overlap can't cover the drain like it does at 4096^3).
// MODE 0: Cout fp32 = C + bias;  MODE 1: scatter bf16 Qh(*kQScale), Kh, Vt[h][d][n]
template<int MODE>
__device__ __forceinline__
void gemm_core(const short* __restrict__ A, const short* __restrict__ BT,
               const float* __restrict__ bias, float* __restrict__ Cout,
               short* __restrict__ Qh, short* __restrict__ Kh, short* __restrict__ Vt,
               int N, int K)
{
    const int bm   = blockIdx.x * 128;
    const int bn   = blockIdx.y * 128;
    const int tid  = threadIdx.x;
    const int wave = tid >> 6;
    const int lane = tid & 63;
    const int l15  = lane & 15;
    const int quad = lane >> 4;
    const int l3   = l15 & 3;

    __shared__ alignas(16) short As[2][128 * 32];
    __shared__ alignas(16) short Bs[2][128 * 32];

    floatx4 acc[4][4] = {};
    const int wm = (wave >> 1) * 64;
    const int wn = (wave & 1) * 64;

    // staging: 16 rows per issue (4 lanes/row), 2 issues/wave per buffer
    const int srl = lane >> 2;               // row within issue group (0..15)
    const int scc = (lane & 3) ^ (srl & 3);  // swizzled source chunk

    const int niter = K / 32;

    // prefetch tile 0 into buffer 0
    #pragma unroll
    for (int j = 0; j < 2; ++j) {
        const int rs = 32 * wave + 16 * j;
        async_copy16(&A [(size_t)(bm + rs + srl) * K + 8 * scc], &As[0][rs * 32]);
        async_copy16(&BT[(size_t)(bn + rs + srl) * K + 8 * scc], &Bs[0][rs * 32]);
    }
    __syncthreads();

    #pragma unroll 2
    for (int it = 0; it < niter; ++it) {
        const int cur = it & 1;
        const int nxt = cur ^ 1;
        if (it + 1 < niter) {
            const int k1 = (it + 1) * 32;
            #pragma unroll
            for (int j = 0; j < 2; ++j) {
                const int rs = 32 * wave + 16 * j;
                async_copy16(&A [(size_t)(bm + rs + srl) * K + k1 + 8 * scc], &As[nxt][rs * 32]);
                async_copy16(&BT[(size_t)(bn + rs + srl) * K + k1 + 8 * scc], &Bs[nxt][rs * 32]);
            }
        }

        bf16x8 af[4], bfr[4];
        #pragma unroll
        for (int mt = 0; mt < 4; ++mt)
            af[mt] = *reinterpret_cast<const bf16x8*>(&As[cur][(wm + 16 * mt + l15) * 32 + 8 * (quad ^ l3)]);
        #pragma unroll
        for (int nt = 0; nt < 4; ++nt)
            bfr[nt] = *reinterpret_cast<const bf16x8*>(&Bs[cur][(wn + 16 * nt + l15) * 32 + 8 * (quad ^ l3)]);
        #pragma unroll
        for (int mt = 0; mt < 4; ++mt)
            #pragma unroll
            for (int nt = 0; nt < 4; ++nt)
                acc[mt][nt] = __builtin_amdgcn_mfma_f32_16x16x32_bf16(af[mt], bfr[nt], acc[mt][nt], 0, 0, 0);

        __syncthreads();   // guards cur reads done + drains nxt prefetch (mostly covered)
    }

    #pragma unroll
    for (int mt = 0; mt < 4; ++mt) {
        #pragma unroll
        for (int nt = 0; nt < 4; ++nt) {
            #pragma unroll
            for (int r = 0; r < 4; ++r) {
                const int row = bm + wm + mt * 16 + 4 * quad + r;
                const int col = bn + wn + nt * 16 + l15;
                float v = acc[mt][nt][r];
                if (MODE == 0) {
                    Cout[(size_t)row * N + col] = v + bias[col];
                } else {
                    const int proj   = col / kD;       // blocks never span projections
                    const int within = col - proj * kD;
                    const int h = within >> 6;
                    const int d = within & 63;
                    if (proj == 0)      Qh[((size_t)h * kN + row) * kHD + d] = f2b(v * kQScale);
                    else if (proj == 1) Kh[((size_t)h * kN + row) * kHD + d] = f2b(v);
                    else                Vt[((size_t)h * kHD + d) * kN + row] = f2b(v);
                }
            }
        }
    }
}

__global__ __launch_bounds__(256)
void gemm_qkv(const short* __restrict__ A, const short* __restrict__ BT,
              short* __restrict__ Qh, short* __restrict__ Kh, short* __restrict__ Vt)
{
    gemm_core<1>(A, BT, nullptr, nullptr, Qh, Kh, Vt, k3D, kD);
}

__global__ __launch_bounds__(256)
void gemm_out(const short* __restrict__ A, const short* __restrict__ BT,
              const float* __restrict__ bias, float* __restrict__ Cout)
{
    gemm_core<0>(A, BT, bias, Cout, nullptr, nullptr, nullptr, kD, kD);
}

// Flash attention, no-max softmax, S^T formulation (unchanged from round 7).
__global__ __launch_bounds__(256)
void attn(const short* __restrict__ Qh, const short* __restrict__ Kh,
          const short* __restrict__ Vt, short* __restrict__ AO)
{
    const int h    = blockIdx.y;
    const int q0   = blockIdx.x * 64;
    const int tid  = threadIdx.x;
    const int wave = tid >> 6;
    const int lane = tid & 63;
    const int l15  = lane & 15;
    const int quad = lane >> 4;
    const int lx   = l15 & 7;

    __shared__ alignas(16) short Ks[128 * 64];  // K tile [kv][d], swizzled
    __shared__ alignas(16) short Vs[64 * 128];  // V^T tile [d][kv], swizzled
    __shared__ alignas(16) short Pm[4 * 2048];  // per-wave P [m=l15][kv], swizzled

    // Q fragments (pre-scaled by kQScale), held for the whole sweep.
    const int qrow = q0 + 16 * wave + l15;
    const size_t qbase = ((size_t)h * kN + qrow) * kHD;
    bf16x8 qf[2];
    qf[0] = *reinterpret_cast<const bf16x8*>(&Qh[qbase + quad * 8]);
    qf[1] = *reinterpret_cast<const bf16x8*>(&Qh[qbase + 32 + quad * 8]);

    floatx4 oacc[4] = {};
    float psum = 0.f;                      // denom partial for Q-row m = l15

    // staging lane constants
    const int krl = lane >> 3;                 // K: row within 8-row issue
    const int kcc = (lane & 7) ^ (krl & 7);    // K: swizzled source chunk
    const int vrl = lane >> 4;                 // V: row within 4-row issue
    const int vp  = lane & 15;                 // V: physical chunk

    short* Pw = Pm + wave * 2048;              // this wave's 16 x 128 P rows

    for (int kv0 = 0; kv0 < kN; kv0 += 128) {
        __syncthreads();   // A: prior tile's K/V reads complete
        #pragma unroll
        for (int j = 0; j < 4; ++j) {
            const int rk = 32 * wave + 8 * j;                       // K rows rk..rk+7
            async_copy16(&Kh[((size_t)h * kN + kv0 + rk + krl) * kHD + 8 * kcc],
                         &Ks[rk * 64]);
            const int rv0 = 16 * wave + 4 * j;                      // V rows rv0..rv0+3
            const int rv  = rv0 + vrl;
            async_copy16(&Vt[((size_t)h * kHD + rv) * kN + kv0 + 8 * (vp ^ (rv & 7))],
                         &Vs[rv0 * 128]);
        }
        __syncthreads();   // B: staging visible

        // S^T = K Q^T (128 kv x 16 m per wave): swap operands, same fragments
        floatx4 sacc[8] = {};
        #pragma unroll
        for (int nt = 0; nt < 8; ++nt) {
            #pragma unroll
            for (int s = 0; s < 2; ++s) {
                bf16x8 kf = *reinterpret_cast<const bf16x8*>(
                    &Ks[(16 * nt + l15) * 64 + 8 * ((4 * s + quad) ^ lx)]);
                sacc[nt] = __builtin_amdgcn_mfma_f32_16x16x32_bf16(kf, qf[s], sacc[nt], 0, 0, 0);
            }
        }

        // p = exp2(s^T); lane holds row m=l15, kv = 16nt+4quad+r -> pack 4 r's
        #pragma unroll
        for (int nt = 0; nt < 8; ++nt) {
            const float p0 = fast_exp2(sacc[nt][0]);
            const float p1 = fast_exp2(sacc[nt][1]);
            const float p2 = fast_exp2(sacc[nt][2]);
            const float p3 = fast_exp2(sacc[nt][3]);
            psum += (p0 + p1) + (p2 + p3);
            bf16x4 pk;
            pk[0] = f2b(p0); pk[1] = f2b(p1); pk[2] = f2b(p2); pk[3] = f2b(p3);
            const int c = 2 * nt + (quad >> 1);
            *reinterpret_cast<bf16x4*>(
                &Pw[l15 * 128 + 8 * (c ^ l15) + 4 * (quad & 1)]) = pk;
        }
        // no barrier: Pw is wave-private; per-wave DS ops complete in order

        // PV: P as A-frag (one b128 per s), V^T rows as B-frag
        #pragma unroll
        for (int s = 0; s < 4; ++s) {
            bf16x8 pa = *reinterpret_cast<const bf16x8*>(
                &Pw[l15 * 128 + 8 * ((4 * s + quad) ^ l15)]);
            #pragma unroll
            for (int dt = 0; dt < 4; ++dt) {
                bf16x8 vv = *reinterpret_cast<const bf16x8*>(
                    &Vs[(16 * dt + l15) * 128 + 8 * ((4 * s + quad) ^ lx)]);
                oacc[dt] = __builtin_amdgcn_mfma_f32_16x16x32_bf16(pa, vv, oacc[dt], 0, 0, 0);
            }
        }
    }

    // denominator: sum across quads, then redistribute to C-layout rows
    float v = psum;
    v += __shfl_xor(v, 16);
    v += __shfl_xor(v, 32);
    float lrow[4];
    #pragma unroll
    for (int r = 0; r < 4; ++r)
        lrow[r] = __shfl(v, 4 * quad + r);   // lane with l15 == 4*quad+r

    #pragma unroll
    for (int dt = 0; dt < 4; ++dt) {
        #pragma unroll
        for (int r = 0; r < 4; ++r) {
            const int row = q0 + 16 * wave + 4 * quad + r;
            const int col = h * kHD + 16 * dt + l15;
            AO[(size_t)row * kD + col] = f2b(oacc[dt][r] / lrow[r]);
        }
    }
}

extern "C" void kernel_launch(void* const* d_in, const int* in_sizes, int n_in,
                              void* d_out, int out_size, void* d_ws, size_t ws_size,
                              hipStream_t stream)
{
    const float* x     = (const float*)d_in[0];  // (4096, 768) fp32
    const float* W_qkv = (const float*)d_in[1];  // (768, 2304) fp32
    const float* W_out = (const float*)d_in[2];  // (768, 768)  fp32
    const float* b_out = (const float*)d_in[3];  // (768,)      fp32
    float* out = (float*)d_out;                  // (4096, 768) fp32

    const size_t HNHD = (size_t)kH * kN * kHD;   // 3,145,728 shorts per tensor
    short* Qh    = (short*)d_ws;                 // [H][N][64]
    short* Kh    = Qh + HNHD;
    short* Vt    = Kh + HNHD;                    // [H][64][N]
    short* Xb    = Vt + HNHD;                    // x bf16 [N][768]; reused as AO
    short* WqkvT = Xb + (size_t)kN * kD;         // [2304][768]
    short* WoutT = WqkvT + (size_t)k3D * kD;     // [768][768]
    short* AO    = Xb;                           // overlay: Xb dead after QKV gemm
    (void)in_sizes; (void)n_in; (void)out_size; (void)ws_size;

    // 0) fused conversions/transposes (one launch)
    prep<<<dim3(kBlkX + kBlkWq + kBlkWo), dim3(256), 0, stream>>>(
        x, W_qkv, W_out, Xb, WqkvT, WoutT);

    // 1) QKV projection + head scatter (Q pre-scaled, V transposed)
    gemm_qkv<<<dim3(kN / 128, k3D / 128), dim3(256), 0, stream>>>(
        Xb, WqkvT, Qh, Kh, Vt);
    // 2) flash attention
    attn<<<dim3(kN / 64, kH), dim3(256), 0, stream>>>(Qh, Kh, Vt, AO);
    // 3) output projection + bias -> fp32
    gemm_out<<<dim3(kN / 128, kD / 128), dim3(256), 0, stream>>>(
        AO, WoutT, b_out, out);
}

// Round 9
// 202.776 us; speedup vs baseline: 1.0074x; 1.0074x over previous
//
#include <hip/hip_runtime.h>
#include <hip/hip_bf16.h>
#include <math.h>

typedef __attribute__((ext_vector_type(8))) short bf16x8;
typedef __attribute__((ext_vector_type(4))) short bf16x4;
typedef __attribute__((ext_vector_type(4))) float floatx4;

constexpr int kN  = 4096;
constexpr int kD  = 768;
constexpr int kH  = 12;
constexpr int kHD = 64;
constexpr int k3D = 2304;
// Q pre-scale: (1/sqrt(64)) * log2(e) so softmax runs in exp2 domain with no muls
constexpr float kQScale = 0.18033688011112042f;

static __device__ __forceinline__ short f2b(float f) {
    __hip_bfloat16 h = __float2bfloat16(f);
    return *reinterpret_cast<short*>(&h);
}

static __device__ __forceinline__ float fast_exp2(float x) {
#if __has_builtin(__builtin_amdgcn_exp2f)
    return __builtin_amdgcn_exp2f(x);
#else
    return exp2f(x);
#endif
}

// Async global->LDS DMA, 16B per lane. LDS dst is wave-uniform base + lane*16.
static __device__ __forceinline__ void async_copy16(const void* g, void* l) {
    __builtin_amdgcn_global_load_lds(
        (const __attribute__((address_space(1))) void*)g,
        (__attribute__((address_space(3))) void*)l, 16, 0, 0);
}

// Fused prep: section 0 = x fp32->bf16; section 1 = W_qkv transpose->bf16;
// section 2 = W_out transpose->bf16.
constexpr int kBlkX  = 1536;            // (4096*768/8)/256
constexpr int kBlkWq = 72 * 24;         // (2304/32) x (768/32)
constexpr int kBlkWo = 24 * 24;         // (768/32) x (768/32)

__global__ __launch_bounds__(256)
void prep(const float* __restrict__ x, const float* __restrict__ Wq,
          const float* __restrict__ Wo, short* __restrict__ Xb,
          short* __restrict__ WqT, short* __restrict__ WoT)
{
    const int bid = blockIdx.x;
    const int tid = threadIdx.x;
    if (bid < kBlkX) {
        const int i = bid * 256 + tid;
        const float4* s = reinterpret_cast<const float4*>(x + (size_t)i * 8);
        float4 a = s[0], b = s[1];
        bf16x8 v;
        v[0] = f2b(a.x); v[1] = f2b(a.y); v[2] = f2b(a.z); v[3] = f2b(a.w);
        v[4] = f2b(b.x); v[5] = f2b(b.y); v[6] = f2b(b.z); v[7] = f2b(b.w);
        *reinterpret_cast<bf16x8*>(Xb + (size_t)i * 8) = v;
        return;
    }
    const float* src; short* dst; int R, C, bx, by;
    if (bid < kBlkX + kBlkWq) {
        const int local = bid - kBlkX;
        src = Wq; dst = WqT; R = kD; C = k3D; bx = local % 72; by = local / 72;
    } else {
        const int local = bid - kBlkX - kBlkWq;
        src = Wo; dst = WoT; R = kD; C = kD; bx = local % 24; by = local / 24;
    }
    __shared__ float t[32][33];
    const int c0 = bx * 32, r0 = by * 32;
    const int tx = tid & 31, ty = tid >> 5;
    #pragma unroll
    for (int i = ty; i < 32; i += 8)
        t[i][tx] = src[(size_t)(r0 + i) * C + c0 + tx];
    __syncthreads();
    #pragma unroll
    for (int i = ty; i < 32; i += 8)
        dst[(size_t)(c0 + i) * R + r0 + tx] = f2b(t[tx][i]);
}

// C[M x N] = A[M x K] * BT[N x K]^T, bf16 in, fp32 acc. 128x128 tile, BK=32.
// Single-buffered m97 structure (r8's dbuf was neutral -> reverted).
template<int MODE>
__device__ __forceinline__
void gemm_core(const short* __restrict__ A, const short* __restrict__ BT,
               const float* __restrict__ bias, float* __restrict__ Cout,
               short* __restrict__ Qh, short* __restrict__ Kh, short* __restrict__ Vt,
               int N, int K)
{
    const int bm   = blockIdx.x * 128;
    const int bn   = blockIdx.y * 128;
    const int tid  = threadIdx.x;
    const int wave = tid >> 6;
    const int lane = tid & 63;
    const int l15  = lane & 15;
    const int quad = lane >> 4;
    const int l3   = l15 & 3;

    __shared__ alignas(16) short As[128 * 32];
    __shared__ alignas(16) short Bs[128 * 32];

    floatx4 acc[4][4] = {};
    const int wm = (wave >> 1) * 64;
    const int wn = (wave & 1) * 64;

    const int srl = lane >> 2;               // row within issue group (0..15)
    const int scc = (lane & 3) ^ (srl & 3);  // swizzled source chunk

    for (int k0 = 0; k0 < K; k0 += 32) {
        __syncthreads();
        #pragma unroll
        for (int j = 0; j < 2; ++j) {
            const int rs = 32 * wave + 16 * j;
            async_copy16(&A [(size_t)(bm + rs + srl) * K + k0 + 8 * scc], &As[rs * 32]);
            async_copy16(&BT[(size_t)(bn + rs + srl) * K + k0 + 8 * scc], &Bs[rs * 32]);
        }
        __syncthreads();

        bf16x8 af[4], bfr[4];
        #pragma unroll
        for (int mt = 0; mt < 4; ++mt)
            af[mt] = *reinterpret_cast<const bf16x8*>(&As[(wm + 16 * mt + l15) * 32 + 8 * (quad ^ l3)]);
        #pragma unroll
        for (int nt = 0; nt < 4; ++nt)
            bfr[nt] = *reinterpret_cast<const bf16x8*>(&Bs[(wn + 16 * nt + l15) * 32 + 8 * (quad ^ l3)]);
        #pragma unroll
        for (int mt = 0; mt < 4; ++mt)
            #pragma unroll
            for (int nt = 0; nt < 4; ++nt)
                acc[mt][nt] = __builtin_amdgcn_mfma_f32_16x16x32_bf16(af[mt], bfr[nt], acc[mt][nt], 0, 0, 0);
    }

    #pragma unroll
    for (int mt = 0; mt < 4; ++mt) {
        #pragma unroll
        for (int nt = 0; nt < 4; ++nt) {
            #pragma unroll
            for (int r = 0; r < 4; ++r) {
                const int row = bm + wm + mt * 16 + 4 * quad + r;
                const int col = bn + wn + nt * 16 + l15;
                float v = acc[mt][nt][r];
                if (MODE == 0) {
                    Cout[(size_t)row * N + col] = v + bias[col];
                } else {
                    const int proj   = col / kD;
                    const int within = col - proj * kD;
                    const int h = within >> 6;
                    const int d = within & 63;
                    if (proj == 0)      Qh[((size_t)h * kN + row) * kHD + d] = f2b(v * kQScale);
                    else if (proj == 1) Kh[((size_t)h * kN + row) * kHD + d] = f2b(v);
                    else                Vt[((size_t)h * kHD + d) * kN + row] = f2b(v);
                }
            }
        }
    }
}

__global__ __launch_bounds__(256)
void gemm_qkv(const short* __restrict__ A, const short* __restrict__ BT,
              short* __restrict__ Qh, short* __restrict__ Kh, short* __restrict__ Vt)
{
    gemm_core<1>(A, BT, nullptr, nullptr, Qh, Kh, Vt, k3D, kD);
}

__global__ __launch_bounds__(256)
void gemm_out(const short* __restrict__ A, const short* __restrict__ BT,
              const float* __restrict__ bias, float* __restrict__ Cout)
{
    gemm_core<0>(A, BT, bias, Cout, nullptr, nullptr, nullptr, kD, kD);
}

// Flash attention, no-max softmax, S^T form, KV-SPLIT wave partitioning:
// each wave owns kv rows [32w, 32w+32) x ALL 64 Q rows. Q is register-resident
// (no LDS Q traffic); K/V fragment reads drop 4x vs Q-split (they were
// replicated across waves). PV is split-K: per-wave partial O, one cross-wave
// LDS reduction at block end (overlays the dead K/V/P regions).
// Grid (N/64, H), 256 threads, BN=128 KV tile. LDS-BW-bound floor ~38 us.
__global__ __launch_bounds__(256, 3)
void attn(const short* __restrict__ Qh, const short* __restrict__ Kh,
          const short* __restrict__ Vt, short* __restrict__ AO)
{
    const int h    = blockIdx.y;
    const int q0   = blockIdx.x * 64;
    const int tid  = threadIdx.x;
    const int wave = tid >> 6;
    const int lane = tid & 63;
    const int l15  = lane & 15;
    const int quad = lane >> 4;
    const int lx   = l15 & 7;
    const int px   = l15 & 3;                  // P swizzle mask (row & 3)

    __shared__ alignas(16) char smem[49920];
    short* Ks = (short*)smem;                  // [128][64] swizzled (16 KB)
    short* Vs = (short*)(smem + 16384);        // [64][128] swizzled (16 KB)
    short* Pm = (short*)(smem + 32768);        // 4 waves x [64 m][32 kv] (16 KB)
    float* Red  = (float*)smem;                // overlay: 3 waves x 16 tiles x 64 lanes x f4
    float* Dred = (float*)(smem + 49152);      // [3][4][16] denom partials

    short* Pw = Pm + wave * 2048;

    // Q fragments: all 64 Q rows (4 m-tiles x 2 d-chunks), B-operand layout,
    // loaded once from global. Pre-scaled by kQScale at QKV epilogue.
    bf16x8 qf[4][2];
    #pragma unroll
    for (int mt = 0; mt < 4; ++mt) {
        const size_t qb = ((size_t)h * kN + q0 + 16 * mt + l15) * kHD + quad * 8;
        qf[mt][0] = *reinterpret_cast<const bf16x8*>(&Qh[qb]);
        qf[mt][1] = *reinterpret_cast<const bf16x8*>(&Qh[qb + 32]);
    }

    floatx4 oacc[4][4] = {};                   // [mt][dt] partial O over wave's kv
    float psum[4] = {0.f, 0.f, 0.f, 0.f};      // [mt] denom partials, row = l15

    // staging lane constants (unchanged from r7)
    const int krl = lane >> 3;
    const int kcc = (lane & 7) ^ (krl & 7);
    const int vrl = lane >> 4;
    const int vp  = lane & 15;

    for (int kv0 = 0; kv0 < kN; kv0 += 128) {
        __syncthreads();   // A: prior tile's K/V/P reads complete
        #pragma unroll
        for (int j = 0; j < 4; ++j) {
            const int rk = 32 * wave + 8 * j;
            async_copy16(&Kh[((size_t)h * kN + kv0 + rk + krl) * kHD + 8 * kcc],
                         &Ks[rk * 64]);
            const int rv0 = 16 * wave + 4 * j;
            const int rv  = rv0 + vrl;
            async_copy16(&Vt[((size_t)h * kHD + rv) * kN + kv0 + 8 * (vp ^ (rv & 7))],
                         &Vs[rv0 * 128]);
        }
        __syncthreads();   // B: staging visible

        // S^T = K Q^T for wave's kv rows: tiles (nt in 0..1) x (mt in 0..3)
        #pragma unroll
        for (int nt = 0; nt < 2; ++nt) {
            const int krow = (32 * wave + 16 * nt + l15) * 64;
            bf16x8 kf0 = *reinterpret_cast<const bf16x8*>(&Ks[krow + 8 * (quad ^ lx)]);
            bf16x8 kf1 = *reinterpret_cast<const bf16x8*>(&Ks[krow + 8 * ((4 + quad) ^ lx)]);
            #pragma unroll
            for (int mt = 0; mt < 4; ++mt) {
                floatx4 sa = {};
                sa = __builtin_amdgcn_mfma_f32_16x16x32_bf16(kf0, qf[mt][0], sa, 0, 0, 0);
                sa = __builtin_amdgcn_mfma_f32_16x16x32_bf16(kf1, qf[mt][1], sa, 0, 0, 0);
                const float p0 = fast_exp2(sa[0]);
                const float p1 = fast_exp2(sa[1]);
                const float p2 = fast_exp2(sa[2]);
                const float p3 = fast_exp2(sa[3]);
                psum[mt] += (p0 + p1) + (p2 + p3);
                bf16x4 pk;
                pk[0] = f2b(p0); pk[1] = f2b(p1); pk[2] = f2b(p2); pk[3] = f2b(p3);
                // row = 16mt+l15 (len 32), logical chunk c = 2nt+(quad>>1), phys = c^px
                *reinterpret_cast<bf16x4*>(
                    &Pw[(16 * mt + l15) * 32 + 8 * ((2 * nt + (quad >> 1)) ^ px) + 4 * (quad & 1)]) = pk;
            }
        }
        // no barrier: Pw wave-private, per-wave DS ops are in-order

        // PV: A = P rows (k = wave's 32 kv), B = V^T rows (chunk 4*wave+quad)
        bf16x8 pa[4];
        #pragma unroll
        for (int mt = 0; mt < 4; ++mt)
            pa[mt] = *reinterpret_cast<const bf16x8*>(
                &Pw[(16 * mt + l15) * 32 + 8 * (quad ^ px)]);
        #pragma unroll
        for (int dt = 0; dt < 4; ++dt) {
            bf16x8 vv = *reinterpret_cast<const bf16x8*>(
                &Vs[(16 * dt + l15) * 128 + 8 * ((4 * wave + quad) ^ lx)]);
            #pragma unroll
            for (int mt = 0; mt < 4; ++mt)
                oacc[mt][dt] = __builtin_amdgcn_mfma_f32_16x16x32_bf16(pa[mt], vv, oacc[mt][dt], 0, 0, 0);
        }
    }

    // intra-wave denom reduction: sum over quads -> every lane holds row l15's
    // sum over this wave's kv range
    #pragma unroll
    for (int mt = 0; mt < 4; ++mt) {
        psum[mt] += __shfl_xor(psum[mt], 16);
        psum[mt] += __shfl_xor(psum[mt], 32);
    }

    __syncthreads();   // all K/V/P reads done -> overlay is safe
    if (wave > 0) {
        float* rb = Red + (wave - 1) * 4096;   // 16 KB region per wave
        #pragma unroll
        for (int mt = 0; mt < 4; ++mt)
            #pragma unroll
            for (int dt = 0; dt < 4; ++dt)
                *reinterpret_cast<floatx4*>(&rb[((mt * 4 + dt) * 64 + lane) * 4]) = oacc[mt][dt];
        if (lane < 16) {
            #pragma unroll
            for (int mt = 0; mt < 4; ++mt)
                Dred[((wave - 1) * 4 + mt) * 16 + l15] = psum[mt];
        }
    }
    __syncthreads();
    if (wave == 0) {
        #pragma unroll
        for (int w = 0; w < 3; ++w) {
            const float* rb = Red + w * 4096;
            #pragma unroll
            for (int mt = 0; mt < 4; ++mt) {
                #pragma unroll
                for (int dt = 0; dt < 4; ++dt) {
                    floatx4 t = *reinterpret_cast<const floatx4*>(&rb[((mt * 4 + dt) * 64 + lane) * 4]);
                    oacc[mt][dt][0] += t[0];
                    oacc[mt][dt][1] += t[1];
                    oacc[mt][dt][2] += t[2];
                    oacc[mt][dt][3] += t[3];
                }
                psum[mt] += Dred[(w * 4 + mt) * 16 + l15];
            }
        }
        #pragma unroll
        for (int mt = 0; mt < 4; ++mt) {
            float lr[4];
            #pragma unroll
            for (int r = 0; r < 4; ++r)
                lr[r] = __shfl(psum[mt], 4 * quad + r);
            #pragma unroll
            for (int dt = 0; dt < 4; ++dt)
                #pragma unroll
                for (int r = 0; r < 4; ++r)
                    AO[(size_t)(q0 + 16 * mt + 4 * quad + r) * kD + h * kHD + 16 * dt + l15] =
                        f2b(oacc[mt][dt][r] / lr[r]);
        }
    }
}

extern "C" void kernel_launch(void* const* d_in, const int* in_sizes, int n_in,
                              void* d_out, int out_size, void* d_ws, size_t ws_size,
                              hipStream_t stream)
{
    const float* x     = (const float*)d_in[0];  // (4096, 768) fp32
    const float* W_qkv = (const float*)d_in[1];  // (768, 2304) fp32
    const float* W_out = (const float*)d_in[2];  // (768, 768)  fp32
    const float* b_out = (const float*)d_in[3];  // (768,)      fp32
    float* out = (float*)d_out;                  // (4096, 768) fp32

    const size_t HNHD = (size_t)kH * kN * kHD;   // 3,145,728 shorts per tensor
    short* Qh    = (short*)d_ws;                 // [H][N][64]
    short* Kh    = Qh + HNHD;
    short* Vt    = Kh + HNHD;                    // [H][64][N]
    short* Xb    = Vt + HNHD;                    // x bf16 [N][768]; reused as AO
    short* WqkvT = Xb + (size_t)kN * kD;         // [2304][768]
    short* WoutT = WqkvT + (size_t)k3D * kD;     // [768][768]
    short* AO    = Xb;                           // overlay: Xb dead after QKV gemm
    (void)in_sizes; (void)n_in; (void)out_size; (void)ws_size;

    // 0) fused conversions/transposes
    prep<<<dim3(kBlkX + kBlkWq + kBlkWo), dim3(256), 0, stream>>>(
        x, W_qkv, W_out, Xb, WqkvT, WoutT);

    // 1) QKV projection + head scatter (Q pre-scaled, V transposed)
    gemm_qkv<<<dim3(kN / 128, k3D / 128), dim3(256), 0, stream>>>(
        Xb, WqkvT, Qh, Kh, Vt);
    // 2) flash attention
    attn<<<dim3(kN / 64, kH), dim3(256), 0, stream>>>(Qh, Kh, Vt, AO);
    // 3) output projection + bias -> fp32
    gemm_out<<<dim3(kN / 128, kD / 128), dim3(256), 0, stream>>>(
        AO, WoutT, b_out, out);
}